// Round 1
// 656.404 us; speedup vs baseline: 1.0333x; 1.0333x over previous
//
#include <hip/hip_runtime.h>
#include <hip/hip_bf16.h>

// Causal MHA forward, B=2 H=16 S=2048 DK=64, fp32 in/out.
// Flash-attention, bf16 MFMA 16x16x32, S^T orientation:
//   S^T = K.Q^T  (A=K-frag, B=Q-frag)  -> per-q stats at lane&15
//   O^T = V^T.P^T (A=V^T-frag, B=P-frag) -> col=lane&15 matches stats
// R5: each wave owns 32 q-rows (2 x 16-row chunks) sharing ONE set of K/V
// fragment reads; block covers 128 q. 512 blocks, 2/CU, all co-resident.
// R6: bijective block->(bh,qblk) remap.
//   Old mapping put identical-qblk blocks (linear ids n, n+256) on the same
//   CU -> heaviest CU did 64 block-iters vs mean 34, and every XCD touched
//   all 32 bh (32MB >> 4MiB L2). New mapping: co-resident pairs have
//   complementary qblk (sum T = 34, uniform makespan) and the SAME bh;
//   each XCD serves exactly 4 bh (4MB K/V ~= L2 capacity).

using bf16x8 = __attribute__((ext_vector_type(8))) short;
using f32x4  = __attribute__((ext_vector_type(4))) float;
using u32x4  = __attribute__((ext_vector_type(4))) unsigned;
using u32x2  = __attribute__((ext_vector_type(2))) unsigned;

#define SEQ  2048
#define DKK  64
#define KSTR 72   // LDS row stride in shorts

__device__ __forceinline__ short f2bf(float f) {   // RNE (used once, for Q)
    union { float f; unsigned u; } v; v.f = f;
    unsigned r = v.u + 0x7fffu + ((v.u >> 16) & 1u);
    return (short)(r >> 16);
}

// pack two floats -> two bf16 in one dword, round-half-up
__device__ __forceinline__ unsigned pkbf(float lo, float hi) {
    union { float f; unsigned u; } a, b; a.f = lo; b.f = hi;
    return __builtin_amdgcn_perm(b.u + 0x8000u, a.u + 0x8000u, 0x07060302u);
}

__global__ __launch_bounds__(256, 2)
void fa_fwd(const float* __restrict__ Qg, const float* __restrict__ Kg,
            const float* __restrict__ Vg, float* __restrict__ Og) {
    __shared__ short Kt[2][64 * KSTR];   // K tile: 64 keys x 64 d (bf16)
    __shared__ short Vt[2][64 * KSTR];   // V^T tile: 64 d x 64 keys (bf16)
    __shared__ short Ps[4][32 * KSTR];   // per-wave P scratch: 32 m x 64 n

    // ---- R6 remap: n -> (xcd, s) -> (bh, qblk)
    //  xcd = n&7 (round-robin XCD dispatch), s = slot within XCD.
    //  bh  = 4*xcd + (s&3): each XCD owns 4 heads -> K/V set fits its L2.
    //  qblk: s<32 descending 15..8, s>=32 ascending 0..7 -> co-resident
    //        pair (s, s+32) has qblk (15-t, t): complementary work.
    const int n    = (int)blockIdx.x + (int)gridDim.x * (int)blockIdx.y; // 0..511
    const int xcd  = n & 7;
    const int s    = n >> 3;                 // 0..63
    const int bh   = 4 * xcd + (s & 3);      // 0..31
    const int q4   = s >> 2;                 // 0..15
    const int qblk = (s < 32) ? (15 - q4) : (q4 - 8);

    const int tid  = threadIdx.x;
    const int lane = tid & 63;
    const int w    = tid >> 6;
    const int m16  = lane & 15;
    const int quad = lane >> 4;

    const size_t hoff = (size_t)bh * SEQ * DKK;
    const float* Qh = Qg + hoff;
    const float* Kh = Kg + hoff;
    const float* Vh = Vg + hoff;
    float*       Oh = Og + hoff;

    const int qb = qblk * 128 + 32 * w;   // wave's first q row (owns 32 rows)

    // staging coordinates (64-key tile per iter)
    const int kn = tid >> 2, kc = tid & 3;              // K: row kn, 16-float chunk kc
    const int vn = (tid & 31) * 2, vd = (tid >> 5) * 8; // V: rows vn,vn+1, d vd..vd+7

    // Q fragments (B-operand layout), 2 chunks of 16 q-rows, scale folded in
    const float cs = 0.18033688011112042f;   // log2(e)/sqrt(64)
    bf16x8 qf[2][2];
    #pragma unroll
    for (int i = 0; i < 2; ++i) {
        const float* qp = Qh + (size_t)(qb + 16 * i + m16) * DKK + quad * 8;
        #pragma unroll
        for (int h = 0; h < 2; ++h) {
            f32x4 a = *(const f32x4*)(qp + 32 * h);
            f32x4 b = *(const f32x4*)(qp + 32 * h + 4);
            bf16x8 f;
            f[0] = f2bf(a[0] * cs); f[1] = f2bf(a[1] * cs);
            f[2] = f2bf(a[2] * cs); f[3] = f2bf(a[3] * cs);
            f[4] = f2bf(b[0] * cs); f[5] = f2bf(b[1] * cs);
            f[6] = f2bf(b[2] * cs); f[7] = f2bf(b[3] * cs);
            qf[i][h] = f;
        }
    }

    float mrun[2] = {-1e30f, -1e30f}, lrun[2] = {0.f, 0.f};
    f32x4 acc[2][4];
    {
        f32x4 z = {0.f, 0.f, 0.f, 0.f};
        #pragma unroll
        for (int i = 0; i < 2; ++i)
            #pragma unroll
            for (int c = 0; c < 4; ++c) acc[i][c] = z;
    }

    f32x4 kr[4], vr[4];
    auto load_tile = [&](int kb) {
        const float* kp = Kh + (size_t)(kb + kn) * DKK + kc * 16;
        #pragma unroll
        for (int i = 0; i < 4; ++i) kr[i] = *(const f32x4*)(kp + 4 * i);
        const float* vp = Vh + (size_t)(kb + vn) * DKK + vd;
        vr[0] = *(const f32x4*)vp;         vr[1] = *(const f32x4*)(vp + 4);
        vr[2] = *(const f32x4*)(vp + DKK); vr[3] = *(const f32x4*)(vp + DKK + 4);
    };
    auto store_tile = [&](int buf) {
        u32x4 A, B;
        A[0] = pkbf(kr[0][0], kr[0][1]); A[1] = pkbf(kr[0][2], kr[0][3]);
        A[2] = pkbf(kr[1][0], kr[1][1]); A[3] = pkbf(kr[1][2], kr[1][3]);
        B[0] = pkbf(kr[2][0], kr[2][1]); B[1] = pkbf(kr[2][2], kr[2][3]);
        B[2] = pkbf(kr[3][0], kr[3][1]); B[3] = pkbf(kr[3][2], kr[3][3]);
        *(u32x4*)&Kt[buf][kn * KSTR + kc * 16]     = A;
        *(u32x4*)&Kt[buf][kn * KSTR + kc * 16 + 8] = B;
        #pragma unroll
        for (int i = 0; i < 8; ++i) {
            const float a = (i < 4) ? vr[0][i] : vr[1][i - 4];   // key vn
            const float b = (i < 4) ? vr[2][i] : vr[3][i - 4];   // key vn+1
            *(unsigned*)&Vt[buf][(vd + i) * KSTR + vn] = pkbf(a, b);
        }
    };

    const int T = 2 * qblk + 2;   // 64-key tiles covering keys 0..qblk*128+127
    load_tile(0);
    store_tile(0);
    __syncthreads();

    for (int t = 0; t < T; ++t) {
        const int cur = t & 1;
        const int kb  = t * 64;
        if (t + 1 < T) load_tile((t + 1) * 64);   // prefetch (covered by compute)

        if (kb <= qb + 31) {   // wave-uniform: tile intersects this wave's range
            // ---- K fragments read ONCE, shared by both q-chunks
            bf16x8 kf[4][2];
            #pragma unroll
            for (int c = 0; c < 4; ++c) {
                kf[c][0] = *(const bf16x8*)&Kt[cur][(16 * c + m16) * KSTR + quad * 8];
                kf[c][1] = *(const bf16x8*)&Kt[cur][(16 * c + m16) * KSTR + 32 + quad * 8];
            }
            // ---- S^T = K.Q^T for both chunks
            f32x4 st0[4], st1[4];
            #pragma unroll
            for (int c = 0; c < 4; ++c) {
                f32x4 z0 = {0.f, 0.f, 0.f, 0.f}, z1 = {0.f, 0.f, 0.f, 0.f};
                z0 = __builtin_amdgcn_mfma_f32_16x16x32_bf16(kf[c][0], qf[0][0], z0, 0, 0, 0);
                z0 = __builtin_amdgcn_mfma_f32_16x16x32_bf16(kf[c][1], qf[0][1], z0, 0, 0, 0);
                z1 = __builtin_amdgcn_mfma_f32_16x16x32_bf16(kf[c][0], qf[1][0], z1, 0, 0, 0);
                z1 = __builtin_amdgcn_mfma_f32_16x16x32_bf16(kf[c][1], qf[1][1], z1, 0, 0, 0);
                st0[c] = z0; st1[c] = z1;
            }

            const bool domask = (kb + 63 > qb);
            short* ps = &Ps[w][0];

            // ---- per-chunk: mask, online softmax, P pack
            #pragma unroll
            for (int i = 0; i < 2; ++i) {
                const int qrow = qb + 16 * i + m16;
                float x[16];
                #pragma unroll
                for (int c = 0; c < 4; ++c) {
                    f32x4 s2 = i ? st1[c] : st0[c];
                    #pragma unroll
                    for (int r = 0; r < 4; ++r) x[4 * c + r] = s2[r];
                }
                if (domask) {
                    #pragma unroll
                    for (int c = 0; c < 4; ++c)
                        #pragma unroll
                        for (int r = 0; r < 4; ++r) {
                            const int nn = kb + 16 * c + quad * 4 + r;
                            if (nn > qrow) x[4 * c + r] = -1e30f;
                        }
                }
                float mx = x[0];
                #pragma unroll
                for (int k = 1; k < 16; ++k) mx = fmaxf(mx, x[k]);
                mx = fmaxf(mx, __shfl_xor(mx, 16));
                mx = fmaxf(mx, __shfl_xor(mx, 32));
                const float mnew  = fmaxf(mrun[i], mx);
                const float alpha = exp2f(mrun[i] - mnew);
                float psum = 0.f;
                #pragma unroll
                for (int k = 0; k < 16; ++k) { x[k] = exp2f(x[k] - mnew); psum += x[k]; }
                psum += __shfl_xor(psum, 16);
                psum += __shfl_xor(psum, 32);
                lrun[i] = lrun[i] * alpha + psum;
                mrun[i] = mnew;
                #pragma unroll
                for (int c = 0; c < 4; ++c)
                    #pragma unroll
                    for (int r = 0; r < 4; ++r) acc[i][c][r] *= alpha;
                #pragma unroll
                for (int c = 0; c < 4; ++c) {
                    u32x2 pk;
                    pk[0] = pkbf(x[4 * c],     x[4 * c + 1]);
                    pk[1] = pkbf(x[4 * c + 2], x[4 * c + 3]);
                    *(u32x2*)&ps[(16 * i + m16) * KSTR + 16 * c + quad * 4] = pk;
                }
            }
            __threadfence_block();   // order wave-local LDS write->read

            bf16x8 pf[2][2];
            #pragma unroll
            for (int i = 0; i < 2; ++i) {
                pf[i][0] = *(const bf16x8*)&ps[(16 * i + m16) * KSTR + quad * 8];
                pf[i][1] = *(const bf16x8*)&ps[(16 * i + m16) * KSTR + 32 + quad * 8];
            }

            // ---- V fragments read ONCE, shared by both q-chunks
            #pragma unroll
            for (int c = 0; c < 4; ++c) {
                const bf16x8 v0 = *(const bf16x8*)&Vt[cur][(16 * c + m16) * KSTR + quad * 8];
                const bf16x8 v1 = *(const bf16x8*)&Vt[cur][(16 * c + m16) * KSTR + 32 + quad * 8];
                acc[0][c] = __builtin_amdgcn_mfma_f32_16x16x32_bf16(v0, pf[0][0], acc[0][c], 0, 0, 0);
                acc[0][c] = __builtin_amdgcn_mfma_f32_16x16x32_bf16(v1, pf[0][1], acc[0][c], 0, 0, 0);
                acc[1][c] = __builtin_amdgcn_mfma_f32_16x16x32_bf16(v0, pf[1][0], acc[1][c], 0, 0, 0);
                acc[1][c] = __builtin_amdgcn_mfma_f32_16x16x32_bf16(v1, pf[1][1], acc[1][c], 0, 0, 0);
            }
        }

        // ---- stage prefetched tile into the other buffer, then single barrier
        if (t + 1 < T) store_tile(cur ^ 1);
        __syncthreads();
    }

    // ---- epilogue: O[qrow][d] = acc / l
    #pragma unroll
    for (int i = 0; i < 2; ++i) {
        const float inv = 1.0f / lrun[i];
        float* op = Oh + (size_t)(qb + 16 * i + m16) * DKK;
        #pragma unroll
        for (int c = 0; c < 4; ++c) {
            f32x4 o;
            #pragma unroll
            for (int r = 0; r < 4; ++r) o[r] = acc[i][c][r] * inv;
            *(f32x4*)(op + c * 16 + quad * 4) = o;
        }
    }
}

extern "C" void kernel_launch(void* const* d_in, const int* in_sizes, int n_in,
                              void* d_out, int out_size, void* d_ws, size_t ws_size,
                              hipStream_t stream) {
    // inputs: [0]=d_model, [1]=num_heads, [2]=Q, [3]=K, [4]=V, [5]=mask(causal -> implicit)
    const float* Q = (const float*)d_in[2];
    const float* K = (const float*)d_in[3];
    const float* V = (const float*)d_in[4];
    float* O = (float*)d_out;
    (void)in_sizes; (void)n_in; (void)out_size; (void)d_ws; (void)ws_size;
    dim3 grid(SEQ / 128, 32 /* B*H */);
    fa_fwd<<<grid, 256, 0, stream>>>(Q, K, V, O);
}